// Round 2
// baseline (313.394 us; speedup 1.0000x reference)
//
#include <hip/hip_runtime.h>

#define H 32
#define Q 64
#define S 8192
#define D 128
#define OBS 16
#define L 2048

// Fused kernel: priority (mean of last OBS attn rows) + avg-pool keys +
// exact top-L binary-radix select + index-sorted compaction.
// One block of 1024 threads per head (32 blocks).
__global__ __launch_bounds__(1024) void k_select(const float* __restrict__ attn,
                                                 int* __restrict__ keep,
                                                 float* __restrict__ hist_out,
                                                 float* __restrict__ pos_out) {
    __shared__ float pr[S];        // 32 KB priority row
    __shared__ int wtot[16];       // per-wave scan totals
    __shared__ int rcount[32];     // one counter per radix round
    const int h = blockIdx.x;
    const int tid = threadIdx.x;
    const int lane = tid & 63, wid = tid >> 6;

    if (tid < 32) rcount[tid] = 0;

    // ---- Stage 1: priority into LDS (coalesced float4, same fp order as ref loop) ----
    {
        const float* abase = attn + ((size_t)(h * Q + (Q - OBS))) * S;
        float4 a0 = make_float4(0.f, 0.f, 0.f, 0.f);
        float4 a1 = make_float4(0.f, 0.f, 0.f, 0.f);
#pragma unroll
        for (int q = 0; q < OBS; ++q) {
            const float4* row = (const float4*)(abase + (size_t)q * S);
            float4 v0 = row[tid];
            float4 v1 = row[tid + 1024];
            a0.x += v0.x; a0.y += v0.y; a0.z += v0.z; a0.w += v0.w;
            a1.x += v1.x; a1.y += v1.y; a1.z += v1.z; a1.w += v1.w;
        }
        const float inv = 1.0f / (float)OBS;
        a0.x *= inv; a0.y *= inv; a0.z *= inv; a0.w *= inv;
        a1.x *= inv; a1.y *= inv; a1.z *= inv; a1.w *= inv;
        ((float4*)pr)[tid] = a0;
        ((float4*)pr)[tid + 1024] = a1;
    }
    __syncthreads();

    // ---- Stage 2: pooled keys (positive floats -> monotone uint bits) ----
    unsigned key[8];
    const int s0 = tid * 8;
    {
        float w[12];
#pragma unroll
        for (int i = 0; i < 12; ++i) {
            int idx = s0 - 2 + i;
            w[i] = (idx >= 0 && idx < S) ? pr[idx] : 0.f;
        }
#pragma unroll
        for (int j = 0; j < 8; ++j) {
            int s = s0 + j;
            float pooled;
            if (s >= S - OBS) {
                pooled = 1.0f;
            } else {
                int lo = s - 2; if (lo < 0) lo = 0;
                int hi = s + 3;            // hi<=S guaranteed outside obs window
                float sum = 0.f;
                for (int i = lo; i < hi; ++i) sum += w[i - s0 + 2];
                pooled = sum / (float)(hi - lo);
            }
            key[j] = __float_as_uint(pooled);
        }
    }

    // ---- Stage 3: binary radix select (1 barrier/round via fresh counters) ----
    unsigned prefix = 0;
    int k = L;
    for (int b = 31; b >= 0; --b) {
        const unsigned bit = 1u << b;
        const unsigned want = prefix | bit;
        const unsigned mask = ~(bit - 1u);
        int cnt = 0;
#pragma unroll
        for (int j = 0; j < 8; ++j) cnt += ((key[j] & mask) == want) ? 1 : 0;
#pragma unroll
        for (int off = 32; off > 0; off >>= 1) cnt += __shfl_down(cnt, off);
        if (lane == 0) atomicAdd(&rcount[b], cnt);
        __syncthreads();
        int total = rcount[b];
        if (total >= k) prefix = want; else k -= total;
    }
    const unsigned T = prefix;
    const int needed_eq = k;   // take this many ==T elements, lowest index first

    // ---- Stage 4: single packed (gt,eq) scan -> output ranks ----
    int gt = 0, eq = 0;
#pragma unroll
    for (int j = 0; j < 8; ++j) {
        gt += (key[j] > T) ? 1 : 0;
        eq += (key[j] == T) ? 1 : 0;
    }
    int packed = (gt << 16) | eq;
    int v = packed;
#pragma unroll
    for (int off = 1; off < 64; off <<= 1) {
        int u = __shfl_up(v, off);
        if (lane >= off) v += u;
    }
    if (lane == 63) wtot[wid] = v;
    __syncthreads();
    int base = 0;
    for (int w = 0; w < wid; ++w) base += wtot[w];
    int excl = base + v - packed;
    int gt_before = excl >> 16;
    int eq_before = excl & 0xffff;

    // ---- Epilogue: scattered writes in index order (already sorted) ----
    {
        int g = gt_before, e = eq_before;
#pragma unroll
        for (int j = 0; j < 8; ++j) {
            bool isgt = key[j] > T;
            bool iseq = key[j] == T;
            bool sel = isgt || (iseq && (e < needed_eq));
            if (sel) {
                int s = s0 + j;
                int rank = g + (e < needed_eq ? e : needed_eq);
                size_t o = (size_t)h * L + rank;
                keep[o] = s;
                pos_out[o] = (float)s;
                hist_out[o] = pr[s];
            }
            g += isgt ? 1 : 0;
            e += iseq ? 1 : 0;
        }
    }
}

// Gather: each 256-thread block handles 8 kept rows; each 32-lane group copies
// one K row AND one V row (float4 per lane, 512 B per row).
__global__ void k_gather(const float* __restrict__ kv_k, const float* __restrict__ kv_v,
                         const int* __restrict__ keep, float* __restrict__ out) {
    const int tid = threadIdx.x;
    const int idx = blockIdx.x * 8 + (tid >> 5);   // h*L + r, 0..H*L-1
    const int lane = tid & 31;
    const int h = idx >> 11;
    const int s = keep[idx];
    const float4* srcK = (const float4*)(kv_k + (size_t)(h * S + s) * D);
    const float4* srcV = (const float4*)(kv_v + (size_t)(h * S + s) * D);
    float4* dstK = (float4*)(out + (size_t)idx * D);
    float4* dstV = (float4*)(out + ((size_t)H * L + idx) * D);
    dstK[lane] = srcK[lane];
    dstV[lane] = srcV[lane];
}

extern "C" void kernel_launch(void* const* d_in, const int* in_sizes, int n_in,
                              void* d_out, int out_size, void* d_ws, size_t ws_size,
                              hipStream_t stream) {
    const float* attn = (const float*)d_in[0];
    const float* k_val = (const float*)d_in[1];
    const float* v_val = (const float*)d_in[2];

    float* out = (float*)d_out;
    float* hist = out + (size_t)2 * H * L * D;   // after k_cache+v_cache
    float* pos = hist + (size_t)H * L;

    int* keep = (int*)d_ws;                      // H*L ints

    k_select<<<H, 1024, 0, stream>>>(attn, keep, hist, pos);
    k_gather<<<(H * L) / 8, 256, 0, stream>>>(k_val, v_val, keep, out);
}

// Round 3
// 297.228 us; speedup vs baseline: 1.0544x; 1.0544x over previous
//
#include <hip/hip_runtime.h>

#define H 32
#define Q 64
#define S 8192
#define D 128
#define OBS 16
#define L 2048

// Kernel 1: priority[h][s] = mean over last OBS queries of attn[0,h,q,s].
// Wide: 256 blocks so the 16 MiB attn read uses all CUs.
__global__ void k_priority(const float* __restrict__ attn, float* __restrict__ prio) {
    int gid = blockIdx.x;              // 0..255
    int h = gid >> 3;                  // 32 heads
    int chunk = gid & 7;               // 8 chunks of 1024 floats
    int s4 = chunk * 1024 + threadIdx.x * 4;
    const float4* base = (const float4*)(attn + ((size_t)(h * Q + (Q - OBS)) * S + s4));
    float4 acc = make_float4(0.f, 0.f, 0.f, 0.f);
#pragma unroll
    for (int qq = 0; qq < OBS; ++qq) {
        float4 v = base[qq * (S / 4)];
        acc.x += v.x; acc.y += v.y; acc.z += v.z; acc.w += v.w;
    }
    const float inv = 1.0f / (float)OBS;
    acc.x *= inv; acc.y *= inv; acc.z *= inv; acc.w *= inv;
    *((float4*)(prio + (size_t)h * S + s4)) = acc;
}

// Kernel 2: avg-pool keys + exact top-L via 4-pass byte-histogram select +
// index-sorted compaction. One 1024-thread block per head.
__global__ __launch_bounds__(1024) void k_select(const float* __restrict__ prio,
                                                 int* __restrict__ keep,
                                                 float* __restrict__ hist_out,
                                                 float* __restrict__ pos_out) {
    __shared__ float pr[S];            // 32 KB priority row
    __shared__ int whist[16][257];     // per-wave histograms, padded (bank = w + b%32 decorrelated)
    __shared__ int wtot[16];
    __shared__ int res_byte, res_k;
    const int h = blockIdx.x;
    const int tid = threadIdx.x;
    const int lane = tid & 63, wid = tid >> 6;

    // ---- load priority row (float4) ----
    {
        const float4* src = (const float4*)(prio + (size_t)h * S);
        ((float4*)pr)[tid] = src[tid];
        ((float4*)pr)[tid + 1024] = src[tid + 1024];
    }
    __syncthreads();

    // ---- pooled keys (positive floats -> monotone uint bits), fp order bit-identical to prior rounds ----
    unsigned key[8];
    const int s0 = tid * 8;
    {
        float w[12];
#pragma unroll
        for (int i = 0; i < 12; ++i) {
            int idx = s0 - 2 + i;
            w[i] = (idx >= 0 && idx < S) ? pr[idx] : 0.f;
        }
#pragma unroll
        for (int j = 0; j < 8; ++j) {
            int s = s0 + j;
            float pooled;
            if (s >= S - OBS) {
                pooled = 1.0f;
            } else {
                int lo = s - 2; if (lo < 0) lo = 0;
                int hi = s + 3;
                float sum = 0.f;
                for (int i = lo; i < hi; ++i) sum += w[i - s0 + 2];
                pooled = sum / (float)(hi - lo);
            }
            key[j] = __float_as_uint(pooled);
        }
    }

    // ---- 4-pass byte-histogram top-L select ----
    unsigned prefix = 0;
    int k = L;
    for (int pass = 3; pass >= 0; --pass) {
        // zero per-wave histograms
        for (int i = tid; i < 16 * 257; i += 1024) ((int*)whist)[i] = 0;
        __syncthreads();
        const int shift = pass * 8;
        // run-length-coalesced atomics (adjacent pooled keys usually share a byte)
        {
            int cur = -1, run = 0;
#pragma unroll
            for (int j = 0; j < 8; ++j) {
                unsigned kk = key[j];
                bool match = (pass == 3) || ((kk >> (shift + 8)) == prefix);
                int b = match ? (int)((kk >> shift) & 255u) : -1;
                if (b != cur) {
                    if (cur >= 0) atomicAdd(&whist[wid][cur], run);
                    cur = b; run = 1;
                } else {
                    run++;
                }
            }
            if (cur >= 0) atomicAdd(&whist[wid][cur], run);
        }
        __syncthreads();
        // wave 0: reduce 16 wave-histograms, suffix-scan, pick threshold byte
        if (wid == 0) {
            int b0 = 0, b1 = 0, b2 = 0, b3 = 0;
            const int bb0 = 4 * lane;
#pragma unroll
            for (int w = 0; w < 16; ++w) {
                b0 += whist[w][bb0 + 0];
                b1 += whist[w][bb0 + 1];
                b2 += whist[w][bb0 + 2];
                b3 += whist[w][bb0 + 3];
            }
            int lane_sum = b0 + b1 + b2 + b3;
            int suffix = lane_sum;   // inclusive suffix over lanes (mirrored Hillis-Steele)
#pragma unroll
            for (int off = 1; off < 64; off <<= 1) {
                int u = __shfl_down(suffix, off);
                if (lane + off < 64) suffix += u;
            }
            int suffix_next = suffix - lane_sum;   // sum over lanes > lane
            if (suffix >= k && suffix_next < k) {  // exactly one crossing lane
                int bins[4] = {b0, b1, b2, b3};
                int cum = suffix_next;
                for (int bb = 3; bb >= 0; --bb) {
                    int nc = cum + bins[bb];
                    if (nc >= k) { res_byte = bb0 + bb; res_k = k - cum; break; }
                    cum = nc;
                }
            }
        }
        __syncthreads();
        prefix = (prefix << 8) | (unsigned)res_byte;
        k = res_k;
    }
    const unsigned T = prefix;
    const int needed_eq = k;   // take this many ==T elements, lowest index first

    // ---- single packed (gt,eq) scan -> output ranks ----
    int gt = 0, eq = 0;
#pragma unroll
    for (int j = 0; j < 8; ++j) {
        gt += (key[j] > T) ? 1 : 0;
        eq += (key[j] == T) ? 1 : 0;
    }
    int packed = (gt << 16) | eq;
    int v = packed;
#pragma unroll
    for (int off = 1; off < 64; off <<= 1) {
        int u = __shfl_up(v, off);
        if (lane >= off) v += u;
    }
    if (lane == 63) wtot[wid] = v;
    __syncthreads();
    int base = 0;
    for (int w = 0; w < wid; ++w) base += wtot[w];
    int excl = base + v - packed;
    int gt_before = excl >> 16;
    int eq_before = excl & 0xffff;

    // ---- epilogue: scattered writes in index order (already sorted) ----
    {
        int g = gt_before, e = eq_before;
#pragma unroll
        for (int j = 0; j < 8; ++j) {
            bool isgt = key[j] > T;
            bool iseq = key[j] == T;
            bool sel = isgt || (iseq && (e < needed_eq));
            if (sel) {
                int s = s0 + j;
                int rank = g + (e < needed_eq ? e : needed_eq);
                size_t o = (size_t)h * L + rank;
                keep[o] = s;
                pos_out[o] = (float)s;
                hist_out[o] = pr[s];
            }
            g += isgt ? 1 : 0;
            e += iseq ? 1 : 0;
        }
    }
}

// Kernel 3: gather selected K/V rows. 8 rows per 256-thread block;
// each 32-lane group copies one K row AND one V row (float4 per lane).
__global__ void k_gather(const float* __restrict__ kv_k, const float* __restrict__ kv_v,
                         const int* __restrict__ keep, float* __restrict__ out) {
    const int tid = threadIdx.x;
    const int idx = blockIdx.x * 8 + (tid >> 5);   // h*L + r
    const int lane = tid & 31;
    const int h = idx >> 11;
    const int s = keep[idx];
    const float4* srcK = (const float4*)(kv_k + (size_t)(h * S + s) * D);
    const float4* srcV = (const float4*)(kv_v + (size_t)(h * S + s) * D);
    float4* dstK = (float4*)(out + (size_t)idx * D);
    float4* dstV = (float4*)(out + ((size_t)H * L + idx) * D);
    dstK[lane] = srcK[lane];
    dstV[lane] = srcV[lane];
}

extern "C" void kernel_launch(void* const* d_in, const int* in_sizes, int n_in,
                              void* d_out, int out_size, void* d_ws, size_t ws_size,
                              hipStream_t stream) {
    const float* attn = (const float*)d_in[0];
    const float* k_val = (const float*)d_in[1];
    const float* v_val = (const float*)d_in[2];

    float* out = (float*)d_out;
    float* hist = out + (size_t)2 * H * L * D;
    float* pos = hist + (size_t)H * L;

    float* prio = (float*)d_ws;                                       // H*S floats = 1 MiB
    int* keep = (int*)((char*)d_ws + (size_t)H * S * sizeof(float));  // H*L ints

    k_priority<<<256, 256, 0, stream>>>(attn, prio);
    k_select<<<H, 1024, 0, stream>>>(prio, keep, hist, pos);
    k_gather<<<(H * L) / 8, 256, 0, stream>>>(k_val, v_val, keep, out);
}